// Round 1
// baseline (833.048 us; speedup 1.0000x reference)
//
#include <hip/hip_runtime.h>

// ---------------------------------------------------------------------------
// VGAE forward on MI355X.
// Layout of d_ws (floats):
//   [0, n)        : deg_src -> out_isqrt
//   [n, 2n)       : deg_dst -> in_isqrt
//   bufA [2n, 2n+64n)        : h_pre (GEMM1 out), later t23 (GEMM23 out)
//   bufB [2n+64n, 2n+128n)   : h_agg (SPMM1 acc), later acc2 (SPMM2 acc)
//   w1t  [.., +512*64)       : W1 transposed  [64 cols][512 k]
//   wct  [.., +64*64)        : [W2|W3] transposed [64 cols][64 k]
// Total: 130n + 36864 floats ~= 52.2 MB
// ---------------------------------------------------------------------------

__global__ __launch_bounds__(256) void k_transpose(
    const float* __restrict__ W1, const float* __restrict__ W2,
    const float* __restrict__ W3, float* __restrict__ w1t,
    float* __restrict__ wct)
{
    int gid = blockIdx.x * 256 + threadIdx.x;
    if (gid < 512 * 64) {
        int c = gid >> 9;          // col 0..63
        int k = gid & 511;         // k 0..511
        w1t[gid] = W1[k * 64 + c];
    }
    int g2 = gid - 512 * 64;
    if (g2 >= 0 && g2 < 64 * 64) {
        int c = g2 >> 6;           // col 0..63
        int k = g2 & 63;           // k 0..63
        wct[g2] = (c < 32) ? W2[k * 32 + c] : W3[k * 32 + (c - 32)];
    }
}

__global__ __launch_bounds__(256) void k_deg(
    const int* __restrict__ src, const int* __restrict__ dst,
    float* __restrict__ deg_src, float* __restrict__ deg_dst, int e)
{
    int gid = blockIdx.x * 256 + threadIdx.x;
    if (gid >= e) return;
    atomicAdd(&deg_src[src[gid]], 1.0f);
    atomicAdd(&deg_dst[dst[gid]], 1.0f);
}

__global__ __launch_bounds__(256) void k_isqrt(float* __restrict__ d, int total)
{
    int gid = blockIdx.x * 256 + threadIdx.x;
    if (gid >= total) return;
    float v = d[gid];
    d[gid] = 1.0f / sqrtf(fmaxf(v, 1.0f));
}

// GEMM1: h_pre[row][col] = out_isqrt[row] * sum_k feat[row][k] * W1[k][col]
// block = 256 threads = 4 waves; 32 rows/block; col = tid&63, 8 rows/thread.
__global__ __launch_bounds__(256) void k_gemm1(
    const float* __restrict__ feat, const float* __restrict__ w1t,
    const float* __restrict__ isq_out, float* __restrict__ h_pre, int n)
{
    __shared__ float sfeat[32][128];   // 16 KB
    const int tid  = threadIdx.x;
    const int col  = tid & 63;
    const int wv   = tid >> 6;
    const int row0 = blockIdx.x * 32;

    float4 acc[8];
#pragma unroll
    for (int i = 0; i < 8; ++i) acc[i] = make_float4(0.f, 0.f, 0.f, 0.f);

    for (int kt = 0; kt < 512; kt += 128) {
        __syncthreads();
        // stage 32 rows x 128 floats (1024 float4 units, 4 per thread)
#pragma unroll
        for (int p = 0; p < 4; ++p) {
            int u  = p * 256 + tid;
            int r  = u >> 5;
            int c4 = u & 31;
            int row = row0 + r;
            float4 v = make_float4(0.f, 0.f, 0.f, 0.f);
            if (row < n)
                v = *(const float4*)&feat[(size_t)row * 512 + kt + c4 * 4];
            *(float4*)&sfeat[r][c4 * 4] = v;
        }
        __syncthreads();

        const float* wp = &w1t[col * 512 + kt];
        const int rb = wv * 8;
        for (int k = 0; k < 128; k += 4) {
            float4 w = *(const float4*)&wp[k];
#pragma unroll
            for (int i = 0; i < 8; ++i) {
                float4 f = *(const float4*)&sfeat[rb + i][k];
                acc[i].x += f.x * w.x;
                acc[i].y += f.y * w.y;
                acc[i].z += f.z * w.z;
                acc[i].w += f.w * w.w;
            }
        }
    }

#pragma unroll
    for (int i = 0; i < 8; ++i) {
        int row = row0 + wv * 8 + i;
        if (row < n) {
            float s = isq_out[row];
            h_pre[(size_t)row * 64 + col] =
                (acc[i].x + acc[i].y + acc[i].z + acc[i].w) * s;
        }
    }
}

// SPMM over edges: y[dst[e]*64+c] += x[src[e]*64+c]; one thread per (edge,col)
__global__ __launch_bounds__(256) void k_spmm64(
    const int* __restrict__ src, const int* __restrict__ dst,
    const float* __restrict__ x, float* __restrict__ y, int total)
{
    int gid = blockIdx.x * 256 + threadIdx.x;
    if (gid >= total) return;
    int e = gid >> 6;
    int c = gid & 63;
    int s = src[e];
    int d = dst[e];
    atomicAdd(&y[(size_t)d * 64 + c], x[(size_t)s * 64 + c]);
}

// GEMM23: stage h = relu(h_agg*in_isqrt + b1)*out_isqrt into LDS, then
// t23[row][col] = sum_k h[row][k] * Wc[k][col]   (Wc = [W2|W3])
__global__ __launch_bounds__(256) void k_gemm23(
    const float* __restrict__ h_agg, const float* __restrict__ wct,
    const float* __restrict__ isq_in, const float* __restrict__ isq_out,
    const float* __restrict__ b1, float* __restrict__ t23, int n)
{
    __shared__ float sh[32][64];   // 8 KB
    const int tid  = threadIdx.x;
    const int col  = tid & 63;
    const int wv   = tid >> 6;
    const int row0 = blockIdx.x * 32;

    // stage 32 rows x 64 floats = 512 float4 units, 2 per thread
#pragma unroll
    for (int p = 0; p < 2; ++p) {
        int u  = p * 256 + tid;
        int r  = u >> 4;
        int c4 = u & 15;
        int row = row0 + r;
        float4 v = make_float4(0.f, 0.f, 0.f, 0.f);
        if (row < n) {
            v = *(const float4*)&h_agg[(size_t)row * 64 + c4 * 4];
            float si = isq_in[row];
            float so = isq_out[row];
            float4 b = *(const float4*)&b1[c4 * 4];
            v.x = fmaxf(v.x * si + b.x, 0.f) * so;
            v.y = fmaxf(v.y * si + b.y, 0.f) * so;
            v.z = fmaxf(v.z * si + b.z, 0.f) * so;
            v.w = fmaxf(v.w * si + b.w, 0.f) * so;
        }
        *(float4*)&sh[r][c4 * 4] = v;
    }
    __syncthreads();

    float4 acc[8];
#pragma unroll
    for (int i = 0; i < 8; ++i) acc[i] = make_float4(0.f, 0.f, 0.f, 0.f);

    const float* wp = &wct[col * 64];
    const int rb = wv * 8;
    for (int k = 0; k < 64; k += 4) {
        float4 w = *(const float4*)&wp[k];
#pragma unroll
        for (int i = 0; i < 8; ++i) {
            float4 f = *(const float4*)&sh[rb + i][k];
            acc[i].x += f.x * w.x;
            acc[i].y += f.y * w.y;
            acc[i].z += f.z * w.z;
            acc[i].w += f.w * w.w;
        }
    }

#pragma unroll
    for (int i = 0; i < 8; ++i) {
        int row = row0 + wv * 8 + i;
        if (row < n)
            t23[(size_t)row * 64 + col] =
                acc[i].x + acc[i].y + acc[i].z + acc[i].w;
    }
}

// final: m = acc2[node][c]*in_isqrt+b2 ; l = acc2[node][32+c]*in_isqrt+b3
//        z = m + noise*exp(l);  out = [z | m | l]
__global__ __launch_bounds__(256) void k_final(
    const float* __restrict__ acc2, const float* __restrict__ isq_in,
    const float* __restrict__ b2, const float* __restrict__ b3,
    const float* __restrict__ noise, float* __restrict__ out, int n)
{
    int gid = blockIdx.x * 256 + threadIdx.x;
    int total = n * 32;
    if (gid >= total) return;
    int node = gid >> 5;
    int c    = gid & 31;
    float si = isq_in[node];
    float m  = acc2[(size_t)node * 64 + c]      * si + b2[c];
    float l  = acc2[(size_t)node * 64 + 32 + c] * si + b3[c];
    float z  = m + noise[gid] * expf(l);
    out[gid]             = z;
    out[total + gid]     = m;
    out[2 * total + gid] = l;
}

extern "C" void kernel_launch(void* const* d_in, const int* in_sizes, int n_in,
                              void* d_out, int out_size, void* d_ws, size_t ws_size,
                              hipStream_t stream)
{
    const float* feat  = (const float*)d_in[0];
    const int*   src   = (const int*)d_in[1];
    const int*   dst   = (const int*)d_in[2];
    const float* noise = (const float*)d_in[3];
    const float* W1    = (const float*)d_in[4];
    const float* b1    = (const float*)d_in[5];
    const float* W2    = (const float*)d_in[6];
    const float* b2    = (const float*)d_in[7];
    const float* W3    = (const float*)d_in[8];
    const float* b3    = (const float*)d_in[9];

    const int n = in_sizes[0] / 512;
    const int e = in_sizes[1];

    float* ws    = (float*)d_ws;
    float* isq   = ws;                         // [2n]: out_isqrt | in_isqrt
    float* bufA  = ws + 2 * (size_t)n;         // [64n] h_pre / t23
    float* bufB  = bufA + 64 * (size_t)n;      // [64n] h_agg / acc2
    float* w1t   = bufB + 64 * (size_t)n;      // [512*64]
    float* wct   = w1t + 512 * 64;             // [64*64]
    float* out   = (float*)d_out;

    // zero degree counters and SPMM1 accumulator
    hipMemsetAsync(isq, 0, 2 * (size_t)n * sizeof(float), stream);
    hipMemsetAsync(bufB, 0, 64 * (size_t)n * sizeof(float), stream);

    k_transpose<<<(512 * 64 + 64 * 64 + 255) / 256, 256, 0, stream>>>(
        W1, W2, W3, w1t, wct);

    k_deg<<<(e + 255) / 256, 256, 0, stream>>>(src, dst, isq, isq + n, e);
    k_isqrt<<<(2 * n + 255) / 256, 256, 0, stream>>>(isq, 2 * n);

    k_gemm1<<<(n + 31) / 32, 256, 0, stream>>>(feat, w1t, isq, bufA, n);

    const int spmm_total = e * 64;
    k_spmm64<<<(spmm_total + 255) / 256, 256, 0, stream>>>(
        src, dst, bufA, bufB, spmm_total);

    k_gemm23<<<(n + 31) / 32, 256, 0, stream>>>(
        bufB, wct, isq + n, isq, b1, bufA, n);

    // re-zero accumulator for SPMM2
    hipMemsetAsync(bufB, 0, 64 * (size_t)n * sizeof(float), stream);
    k_spmm64<<<(spmm_total + 255) / 256, 256, 0, stream>>>(
        src, dst, bufA, bufB, spmm_total);

    k_final<<<(n * 32 + 255) / 256, 256, 0, stream>>>(
        bufB, isq + n, b2, b3, noise, out, n);
}

// Round 2
// 376.350 us; speedup vs baseline: 2.2135x; 2.2135x over previous
//
#include <hip/hip_runtime.h>

// ---------------------------------------------------------------------------
// VGAE forward, round 2: LDS-tiled f32 GEMM (W in natural [k][64] layout),
// CSR-gather SPMM (no f32 atomics), fused epilogues.
//
// d_ws layout (floats then ints):
//   isq_out [n], isq_in [n]
//   bufA [64n]  : h_pre (gemm1 out) -> t23 (gemm23 out)
//   bufB [64n]  : h (gather1 out, gemm23 in)
//   wc   [64*64]: [W2|W3] combined, natural [k][col]
//   ints: row_ptr[n+1], cursor[n], partials[512], edge_src[e]
//   (degS/degD ints overlay bufA before gemm1 runs)
// ---------------------------------------------------------------------------

__global__ __launch_bounds__(256) void k_build_wc(
    const float* __restrict__ W2, const float* __restrict__ W3,
    float* __restrict__ wc)
{
    int gid = blockIdx.x * 256 + threadIdx.x;
    if (gid >= 64 * 64) return;
    int k = gid >> 6, c = gid & 63;
    wc[gid] = (c < 32) ? W2[k * 32 + c] : W3[k * 32 + (c - 32)];
}

__global__ __launch_bounds__(256) void k_deg_int(
    const int* __restrict__ src, const int* __restrict__ dst,
    int* __restrict__ degS, int* __restrict__ degD, int e)
{
    int gid = blockIdx.x * 256 + threadIdx.x;
    if (gid >= e) return;
    atomicAdd(&degS[src[gid]], 1);
    atomicAdd(&degD[dst[gid]], 1);
}

__global__ __launch_bounds__(256) void k_isqrt2(
    const int* __restrict__ degS, const int* __restrict__ degD,
    float* __restrict__ isq_out, float* __restrict__ isq_in, int n)
{
    int gid = blockIdx.x * 256 + threadIdx.x;
    if (gid >= n) return;
    isq_out[gid] = 1.0f / sqrtf((float)max(degS[gid], 1));
    isq_in[gid]  = 1.0f / sqrtf((float)max(degD[gid], 1));
}

// ---- 3-pass exclusive scan of degD -> row_ptr / cursor ----
__global__ __launch_bounds__(256) void k_scan_block_sums(
    const int* __restrict__ deg, int* __restrict__ partials, int n)
{
    __shared__ int red[256];
    int gid = blockIdx.x * 256 + threadIdx.x;
    red[threadIdx.x] = (gid < n) ? deg[gid] : 0;
    __syncthreads();
    for (int s = 128; s > 0; s >>= 1) {
        if (threadIdx.x < s) red[threadIdx.x] += red[threadIdx.x + s];
        __syncthreads();
    }
    if (threadIdx.x == 0) partials[blockIdx.x] = red[0];
}

__global__ __launch_bounds__(512) void k_scan_partials(
    int* __restrict__ partials, int nb)   // nb <= 512, exclusive in place
{
    __shared__ int s[512];
    int t = threadIdx.x;
    s[t] = (t < nb) ? partials[t] : 0;
    __syncthreads();
    for (int d = 1; d < 512; d <<= 1) {
        int v = (t >= d) ? s[t - d] : 0;
        __syncthreads();
        s[t] += v;
        __syncthreads();
    }
    if (t < nb) partials[t] = (t == 0) ? 0 : s[t - 1];
}

__global__ __launch_bounds__(256) void k_scan_final(
    const int* __restrict__ deg, const int* __restrict__ partials,
    int* __restrict__ row_ptr, int* __restrict__ cursor, int n)
{
    __shared__ int s[256];
    int t = threadIdx.x;
    int gid = blockIdx.x * 256 + t;
    int v = (gid < n) ? deg[gid] : 0;
    s[t] = v;
    __syncthreads();
    for (int d = 1; d < 256; d <<= 1) {
        int u = (t >= d) ? s[t - d] : 0;
        __syncthreads();
        s[t] += u;
        __syncthreads();
    }
    int start = partials[blockIdx.x] + s[t] - v;   // exclusive
    if (gid < n) { row_ptr[gid] = start; cursor[gid] = start; }
    if (gid == n - 1) row_ptr[n] = start + v;
}

__global__ __launch_bounds__(256) void k_scatter(
    const int* __restrict__ src, const int* __restrict__ dst,
    int* __restrict__ cursor, int* __restrict__ edge_src, int e)
{
    int gid = blockIdx.x * 256 + threadIdx.x;
    if (gid >= e) return;
    int pos = atomicAdd(&cursor[dst[gid]], 1);
    edge_src[pos] = src[gid];
}

// ---- tiled GEMM: Y[n][64] = X[n][K] @ W[K][64], optional row scale ----
// block 256 = 4 waves, tile 64 rows x 64 cols; thread = 8 rows x 2 cols.
template <int K, bool SCALE>
__global__ __launch_bounds__(256) void k_gemm(
    const float* __restrict__ X, const float* __restrict__ W,
    const float* __restrict__ scale, float* __restrict__ Y, int n)
{
    constexpr int KT = 64;
    __shared__ float sx[64][KT + 4];   // stride 68: bank (4r+k)%32, 2 addr/wave
    __shared__ float sw[KT][64];       // read f2 at k*64+2c: 2-way, free
    const int tid  = threadIdx.x;
    const int colp = tid & 31;         // cols {2colp, 2colp+1}
    const int rg   = tid >> 5;         // rows rg*8 .. rg*8+7
    const int row0 = blockIdx.x * 64;

    float2 acc[8];
#pragma unroll
    for (int i = 0; i < 8; ++i) acc[i] = make_float2(0.f, 0.f);

    for (int kt = 0; kt < K; kt += KT) {
        __syncthreads();
#pragma unroll
        for (int p = 0; p < 4; ++p) {           // stage X tile
            int u = p * 256 + tid;
            int r = u >> 4, c4 = (u & 15) * 4;
            int row = row0 + r;
            float4 v = make_float4(0.f, 0.f, 0.f, 0.f);
            if (row < n) v = *(const float4*)&X[(size_t)row * K + kt + c4];
            *(float4*)&sx[r][c4] = v;
        }
#pragma unroll
        for (int p = 0; p < 4; ++p) {           // stage W tile
            int u = p * 256 + tid;
            int kk = u >> 4, c4 = (u & 15) * 4;
            *(float4*)&sw[kk][c4] = *(const float4*)&W[(size_t)(kt + kk) * 64 + c4];
        }
        __syncthreads();
#pragma unroll 4
        for (int k4 = 0; k4 < KT; k4 += 4) {
            float2 w0 = *(const float2*)&sw[k4 + 0][colp * 2];
            float2 w1 = *(const float2*)&sw[k4 + 1][colp * 2];
            float2 w2 = *(const float2*)&sw[k4 + 2][colp * 2];
            float2 w3 = *(const float2*)&sw[k4 + 3][colp * 2];
#pragma unroll
            for (int i = 0; i < 8; ++i) {
                float4 f = *(const float4*)&sx[rg * 8 + i][k4];
                acc[i].x += f.x * w0.x + f.y * w1.x + f.z * w2.x + f.w * w3.x;
                acc[i].y += f.x * w0.y + f.y * w1.y + f.z * w2.y + f.w * w3.y;
            }
        }
    }
#pragma unroll
    for (int i = 0; i < 8; ++i) {
        int row = row0 + rg * 8 + i;
        if (row < n) {
            float s = SCALE ? scale[row] : 1.0f;
            float2 o = make_float2(acc[i].x * s, acc[i].y * s);
            *(float2*)&Y[(size_t)row * 64 + colp * 2] = o;
        }
    }
}

// ---- gather SPMM 1: h = relu(sum * isq_in + b1) * isq_out ----
__global__ __launch_bounds__(256) void k_gather_h(
    const int* __restrict__ row_ptr, const int* __restrict__ edge_src,
    const float* __restrict__ x, const float* __restrict__ isq_in,
    const float* __restrict__ isq_out, const float* __restrict__ b1,
    float* __restrict__ h, int n)
{
    int col  = threadIdx.x & 63;
    int node = __builtin_amdgcn_readfirstlane(blockIdx.x * 4 + (threadIdx.x >> 6));
    if (node >= n) return;
    int j = row_ptr[node], jend = row_ptr[node + 1];
    float a0 = 0.f, a1 = 0.f, a2 = 0.f, a3 = 0.f;
    for (; j + 3 < jend; j += 4) {
        int e0 = edge_src[j], e1 = edge_src[j + 1];
        int e2 = edge_src[j + 2], e3 = edge_src[j + 3];
        a0 += x[(size_t)e0 * 64 + col];
        a1 += x[(size_t)e1 * 64 + col];
        a2 += x[(size_t)e2 * 64 + col];
        a3 += x[(size_t)e3 * 64 + col];
    }
    for (; j < jend; ++j) a0 += x[(size_t)edge_src[j] * 64 + col];
    float acc = (a0 + a1) + (a2 + a3);
    h[(size_t)node * 64 + col] =
        fmaxf(acc * isq_in[node] + b1[col], 0.f) * isq_out[node];
}

// ---- gather SPMM 2 fused with final: out = [z | mean | log_std] ----
__global__ __launch_bounds__(256) void k_gather_final(
    const int* __restrict__ row_ptr, const int* __restrict__ edge_src,
    const float* __restrict__ t23, const float* __restrict__ isq_in,
    const float* __restrict__ b2, const float* __restrict__ b3,
    const float* __restrict__ noise, float* __restrict__ out, int n)
{
    int lane = threadIdx.x & 63;
    int node = __builtin_amdgcn_readfirstlane(blockIdx.x * 4 + (threadIdx.x >> 6));
    if (node >= n) return;
    int j = row_ptr[node], jend = row_ptr[node + 1];
    float a0 = 0.f, a1 = 0.f, a2 = 0.f, a3 = 0.f;
    for (; j + 3 < jend; j += 4) {
        int e0 = edge_src[j], e1 = edge_src[j + 1];
        int e2 = edge_src[j + 2], e3 = edge_src[j + 3];
        a0 += t23[(size_t)e0 * 64 + lane];
        a1 += t23[(size_t)e1 * 64 + lane];
        a2 += t23[(size_t)e2 * 64 + lane];
        a3 += t23[(size_t)e3 * 64 + lane];
    }
    for (; j < jend; ++j) a0 += t23[(size_t)edge_src[j] * 64 + lane];
    float acc = (a0 + a1) + (a2 + a3);
    float si = isq_in[node];
    float v  = acc * si + (lane < 32 ? b2[lane] : b3[lane - 32]);
    float lv = __shfl(v, lane | 32, 64);       // log_std partner value
    int total = n * 32;
    int base  = node * 32 + (lane & 31);
    if (lane < 32) {
        float z = v + noise[base] * expf(lv);
        out[base]         = z;                 // z
        out[total + base] = v;                 // mean
    } else {
        out[2 * total + base] = v;             // log_std
    }
}

extern "C" void kernel_launch(void* const* d_in, const int* in_sizes, int n_in,
                              void* d_out, int out_size, void* d_ws, size_t ws_size,
                              hipStream_t stream)
{
    const float* feat  = (const float*)d_in[0];
    const int*   src   = (const int*)d_in[1];
    const int*   dst   = (const int*)d_in[2];
    const float* noise = (const float*)d_in[3];
    const float* W1    = (const float*)d_in[4];   // [512][64] natural
    const float* b1    = (const float*)d_in[5];
    const float* W2    = (const float*)d_in[6];
    const float* b2    = (const float*)d_in[7];
    const float* W3    = (const float*)d_in[8];
    const float* b3    = (const float*)d_in[9];

    const int n = in_sizes[0] / 512;
    const int e = in_sizes[1];

    float* ws      = (float*)d_ws;
    float* isq_out = ws;
    float* isq_in  = ws + n;
    float* bufA    = ws + 2 * (size_t)n;            // h_pre -> t23
    float* bufB    = bufA + 64 * (size_t)n;         // h
    float* wc      = bufB + 64 * (size_t)n;         // 4096
    int*   ip      = (int*)(wc + 64 * 64);
    int* row_ptr   = ip;                            // n+1
    int* cursor    = ip + (n + 1);                  // n
    int* partials  = cursor + n;                    // 512
    int* edge_src  = partials + 512;                // e
    // transient degree histograms overlay bufA (free until gemm1 runs)
    int* degS = (int*)bufA;
    int* degD = degS + n;
    float* out = (float*)d_out;

    const int nb = (n + 255) / 256;                 // scan blocks (391)

    hipMemsetAsync(degS, 0, 2 * (size_t)n * sizeof(int), stream);

    k_build_wc<<<(64 * 64 + 255) / 256, 256, 0, stream>>>(W2, W3, wc);
    k_deg_int<<<(e + 255) / 256, 256, 0, stream>>>(src, dst, degS, degD, e);
    k_isqrt2<<<nb, 256, 0, stream>>>(degS, degD, isq_out, isq_in, n);

    k_scan_block_sums<<<nb, 256, 0, stream>>>(degD, partials, n);
    k_scan_partials<<<1, 512, 0, stream>>>(partials, nb);
    k_scan_final<<<nb, 256, 0, stream>>>(degD, partials, row_ptr, cursor, n);
    k_scatter<<<(e + 255) / 256, 256, 0, stream>>>(src, dst, cursor, edge_src, e);

    k_gemm<512, true><<<(n + 63) / 64, 256, 0, stream>>>(
        feat, W1, isq_out, bufA, n);

    k_gather_h<<<(n + 3) / 4, 256, 0, stream>>>(
        row_ptr, edge_src, bufA, isq_in, isq_out, b1, bufB, n);

    k_gemm<64, false><<<(n + 63) / 64, 256, 0, stream>>>(
        bufB, wc, nullptr, bufA, n);

    k_gather_final<<<(n + 3) / 4, 256, 0, stream>>>(
        row_ptr, edge_src, bufA, isq_in, b2, b3, noise, out, n);
}